// Round 12
// baseline (219.733 us; speedup 1.0000x reference)
//
#include <hip/hip_runtime.h>
#include <hip/hip_bf16.h>

#define B_  4
#define D_  1024
#define L_  2048
#define H_  8
#define HD_ 128

typedef __attribute__((ext_vector_type(8))) short bf16x8;
typedef __attribute__((ext_vector_type(4))) float f32x4;
typedef __attribute__((ext_vector_type(2))) unsigned uint2v;
typedef __attribute__((ext_vector_type(4))) unsigned uint4v;

#if __has_builtin(__builtin_amdgcn_permlane16_swap) && __has_builtin(__builtin_amdgcn_permlane32_swap)
#define HAS_PERMSWAP 1
#else
#define HAS_PERMSWAP 0
#endif

static __device__ __forceinline__ ushort f2bf(float f) {
    // round-to-nearest-even fp32 -> bf16 (finite inputs only)
    unsigned u = __float_as_uint(f);
    unsigned r = (u + 0x7fffu + ((u >> 16) & 1u)) >> 16;
    return (ushort)r;
}

// packed fp32x2 -> bf16x2 (RNE) in one instruction; lo = first arg
static __device__ __forceinline__ unsigned cvt_pk_bf16(float lo, float hi) {
    unsigned r;
    asm("v_cvt_pk_bf16_f32 %0, %1, %2" : "=v"(r) : "v"(lo), "v"(hi));
    return r;
}

// hardware exp2 (v_exp_f32)
static __device__ __forceinline__ float exp2_fast(float x) {
#if __has_builtin(__builtin_amdgcn_exp2f)
    return __builtin_amdgcn_exp2f(x);
#else
    return exp2f(x);
#endif
}

// max over the 4 quads (lanes {li, li+16, li+32, li+48}) — pure VALU if permlane
static __device__ __forceinline__ float qmax4(float x) {
#if HAS_PERMSWAP
    uint2v a = __builtin_amdgcn_permlane16_swap(__float_as_uint(x), __float_as_uint(x), false, false);
    float y = fmaxf(__uint_as_float(a[0]), __uint_as_float(a[1]));
    uint2v b = __builtin_amdgcn_permlane32_swap(__float_as_uint(y), __float_as_uint(y), false, false);
    return fmaxf(__uint_as_float(b[0]), __uint_as_float(b[1]));
#else
    x = fmaxf(x, __shfl_xor(x, 16, 64));
    return fmaxf(x, __shfl_xor(x, 32, 64));
#endif
}

// async 16B global->LDS DMA (dest = wave-uniform LDS base + lane*16)
static __device__ __forceinline__ void dma16(const ushort* g, ushort* l) {
    __builtin_amdgcn_global_load_lds(
        (const __attribute__((address_space(1))) void*)g,
        (__attribute__((address_space(3))) void*)l, 16, 0, 0);
}

// ---------------- signal kernel: zero output ----------------
__global__ void k_zero_out(float* __restrict__ out, int n) {
    int i = blockIdx.x * 256 + threadIdx.x;
    if (i < n) out[i] = 0.f;
}

// ---------------- Kernel A (fused prep): scan | transpose | convert_w -----------
// role by blockIdx range (block-uniform): [0,4) mask scan (FIRST so its serial
// waves overlap the bulk, no tail), [4,2052) transpose 64x64, [2052,5124) convert.
__global__ void k_prep(const float* __restrict__ q, const float* __restrict__ W1,
                       const float* __restrict__ Wq, const int* __restrict__ mask,
                       ushort* __restrict__ Wb, ushort* __restrict__ Xt,
                       int* __restrict__ cidx, int* __restrict__ cnt) {
    __shared__ float tile[64][65];     // 16.6 KB (transpose role)
    const int bid = blockIdx.x, t = threadIdx.x;
    if (bid < 4) {
        // mask scan: cidx[b][j] = original l of j-th unmasked key; pad 0; cnt[b]
        int b = bid;
        if (t < 64) {
            int lane = t;
            const int* mb = mask + b * L_;
            int base = 0;
            for (int c = 0; c < L_; c += 64) {
                int m = mb[c + lane];
                unsigned long long bal = __ballot(m != 0);
                int pre = __popcll(bal & ((1ull << lane) - 1ull));
                if (m) cidx[b * L_ + base + pre] = c + lane;
                base += __popcll(bal);
            }
            for (int j = base + lane; j < L_; j += 64) cidx[b * L_ + j] = 0;
            if (lane == 0) cnt[b] = base;
        }
    } else if (bid < 4 + 2048) {
        // transpose query[b][d][l] fp32 -> Xt[b][l][d] bf16, 64x64 tile
        int tb = bid - 4;
        int bx = tb & 31, by = (tb >> 5) & 15, bz = tb >> 9;
        int l0 = bx * 64, d0 = by * 64;
        int rr = t >> 4, cc = t & 15;            // rr 0..15, cc 0..15
        const float* src = q + (size_t)bz * D_ * L_;
        for (int i = 0; i < 4; i++) {
            int r = rr + 16 * i;                 // d-row 0..63
            float4 v = *(const float4*)&src[(size_t)(d0 + r) * L_ + l0 + cc * 4];
            tile[r][cc * 4 + 0] = v.x;
            tile[r][cc * 4 + 1] = v.y;
            tile[r][cc * 4 + 2] = v.z;
            tile[r][cc * 4 + 3] = v.w;
        }
        __syncthreads();
        ushort* dst = Xt + (size_t)bz * L_ * D_;
        for (int i = 0; i < 4; i++) {
            int lr = rr + 16 * i;                // l-row 0..63
            uint2 o;
            o.x = cvt_pk_bf16(tile[cc * 4 + 0][lr], tile[cc * 4 + 1][lr]);
            o.y = cvt_pk_bf16(tile[cc * 4 + 2][lr], tile[cc * 4 + 3][lr]);
            *(uint2*)&dst[(size_t)(l0 + lr) * D_ + d0 + cc * 4] = o;
        }
    } else {
        // W1||Wq fp32 -> bf16 Wb [3072][1024]
        int i = (bid - 2052) * 256 + t;
        const int n1 = 2 * D_ * D_ / 4;
        float4 v = (i < n1) ? ((const float4*)W1)[i] : ((const float4*)Wq)[i - n1];
        ushort4 o;
        o.x = f2bf(v.x); o.y = f2bf(v.y); o.z = f2bf(v.z); o.w = f2bf(v.w);
        ((ushort4*)Wb)[i] = o;
    }
}

// ---------------- Kernel B: projection GEMM (MFMA, XCD supertiles) --------------
// Staging: r9-proven single-buffer issue->drain (2 barriers/K-step, BK=64,
// cross-block TLP hides the drain — pipelined variants measured SLOWER: r6/r11).
// bid -> XCD-chunked 4x4 supertile decode (FETCH 87->46 MB, proven r6/r7).
// NEW: epilogue stages the output tile in the (dead) staging LDS, padded rows,
// then streams 128 B contiguous per thread — replaces 8B/2B scattered stores.
__launch_bounds__(256)
__global__ void k_proj(const ushort* __restrict__ Wb, const ushort* __restrict__ Xt,
                       const int* __restrict__ cidx, const int* __restrict__ cnt,
                       ushort* __restrict__ Qb, ushort* __restrict__ Kb,
                       ushort* __restrict__ Vt) {
    // 34816 B: K-loop uses [0,32KB) as As|Bs; epilogue reuses all as 128x136 tile
    __shared__ alignas(16) ushort sh[128 * 136];
    ushort* As = sh;            // 128 x 64 ushorts (16 KB), swizzled content
    ushort* Bs = sh + 8192;     // 128 x 64 ushorts (16 KB)
    // ---- XCD-chunked supertile decode (bijective on 1536) ----
    const int bid = blockIdx.x;
    const int xcd = bid & 7, j = bid >> 3;       // j 0..191: per-XCD stream
    const int wid = xcd * 192 + j;               // contiguous chunk per XCD
    const int st = wid >> 4, m = wid & 15;       // supertile 0..95, member 0..15
    const int b  = st / 24;                      // batch
    const int sr = st % 24;
    const int sx = sr & 3, sy = sr >> 2;         // supergrid 4x x 6y
    const int x  = sx * 4 + (m & 3);             // l-tile 0..15
    const int y  = sy * 4 + (m >> 2);            // o-tile 0..23
    const int o0 = y * 128;
    const int l0 = x * 128;
    const int type = o0 >> 10;                   // 0=K 1=V 2=Q (tile never crosses)
    if (type < 2) {                              // compacted key space: skip dead tiles
        int tiles = (cnt[b] + 127) >> 7;
        if (x >= tiles) return;                  // uniform; before any barrier
    }
    const int t = threadIdx.x;
    const int wave = t >> 6, lane = t & 63, quad = lane >> 4, li = lane & 15;
    const int wm = wave >> 1, wn = wave & 1;
    const ushort* Xb = Xt + (size_t)b * L_ * D_;

    // staging: slot s = i*256 + t -> row = i*32 + (t>>3), phys chunk p = t&7
    // slot (row,p) holds global 16B chunk g = p ^ (row&7)
    const int srow = t >> 3;
    const int g = (t & 7) ^ (srow & 7);
    const ushort* aSrc[4];
    const ushort* bSrc[4];
    for (int i = 0; i < 4; i++) {
        int r = i * 32 + srow;
        aSrc[i] = Wb + (size_t)(o0 + r) * D_ + g * 8;
        int l = l0 + r;
        int gl = (type < 2) ? cidx[b * L_ + l] : l;
        bSrc[i] = Xb + (size_t)gl * D_ + g * 8;
    }

    f32x4 acc[4][4] = {};

    for (int k0 = 0; k0 < D_; k0 += 64) {
        for (int i = 0; i < 4; i++)
            dma16(aSrc[i] + k0, &As[(i * 256 + wave * 64) * 8]);
        for (int i = 0; i < 4; i++)
            dma16(bSrc[i] + k0, &Bs[(i * 256 + wave * 64) * 8]);
        __syncthreads();   // vmcnt(0) drain; cross-block TLP covers the latency
        for (int ks = 0; ks < 64; ks += 32) {
            const int kc = ks >> 3;
            bf16x8 af[4], bfr[4];
            for (int mf = 0; mf < 4; mf++) {
                int row = wm * 64 + mf * 16 + li;
                af[mf] = *(const bf16x8*)&As[row * 64 + (((kc + quad) ^ (li & 7)) * 8)];
            }
            for (int nf = 0; nf < 4; nf++) {
                int row = wn * 64 + nf * 16 + li;
                bfr[nf] = *(const bf16x8*)&Bs[row * 64 + (((kc + quad) ^ (li & 7)) * 8)];
            }
            for (int mf = 0; mf < 4; mf++)
                for (int nf = 0; nf < 4; nf++)
                    acc[mf][nf] = __builtin_amdgcn_mfma_f32_16x16x32_bf16(af[mf], bfr[nf], acc[mf][nf], 0, 0, 0);
        }
        __syncthreads();   // all fragment reads done before next tile's DMA lands
    }
    // (trailing barrier above guarantees everyone is done with As/Bs)

    // ---- epilogue: LDS-staged transpose -> coalesced 128B/thread stores ----
    // K/Q: sh[l_local][hd_local]; V: sh[hd_local][l_local]; row stride 136 (16B-aligned, bank-spread)
    const int h = (o0 & 1023) >> 7;              // block-uniform head
    const float qscale = 0.1275174495450826f;    // HD^-0.5 * log2(e)
    const float sc = (type == 2) ? qscale : 1.0f;
    for (int mf = 0; mf < 4; mf++) {
        int hd0 = wm * 64 + mf * 16 + quad * 4;
        for (int nf = 0; nf < 4; nf++) {
            int ll = wn * 64 + nf * 16 + li;
            f32x4 v = acc[mf][nf];
            if (type == 1) {
                sh[(hd0 + 0) * 136 + ll] = f2bf(v[0]);
                sh[(hd0 + 1) * 136 + ll] = f2bf(v[1]);
                sh[(hd0 + 2) * 136 + ll] = f2bf(v[2]);
                sh[(hd0 + 3) * 136 + ll] = f2bf(v[3]);
            } else {
                uint2 p;
                p.x = cvt_pk_bf16(v[0] * sc, v[1] * sc);
                p.y = cvt_pk_bf16(v[2] * sc, v[3] * sc);
                *(uint2*)&sh[ll * 136 + hd0] = p;
            }
        }
    }
    __syncthreads();
    {
        int row = t >> 1, seg = t & 1;           // 128 rows x 2 half-rows of 128B
        ushort* dst;
        if (type == 1)
            dst = Vt + ((size_t)(b * H_ + h) * HD_ + row) * L_ + l0 + seg * 64;
        else if (type == 0)
            dst = Kb + ((size_t)(b * H_ + h) * L_ + l0 + row) * HD_ + seg * 64;
        else
            dst = Qb + ((size_t)(b * H_ + h) * L_ + l0 + row) * HD_ + seg * 64;
        const ushort* srcl = &sh[row * 136 + seg * 64];
        for (int k = 0; k < 8; k++)
            *(uint4*)(dst + k * 8) = *(const uint4*)(srcl + k * 8);
    }
}

// ---------------- Kernel C: flash attention over COMPACTED keys ------------------
// block = (b, h, 64 q); 4 waves x 16 q; key blocks of 32; one barrier/iter.
// Softmax critical path has ZERO DS ops: max via permlane swaps (VALU), row-sum
// via one extra MFMA into a persistent row-space accumulator, P redistribution
// via permlane (no LDS round-trip). defer-max THR=8 (log2 units): keep a stale
// running max while tile maxes stay within 2^8 headroom -> rescale pass rare.
__launch_bounds__(256, 4)
__global__ void k_attn(const ushort* __restrict__ Qb, const ushort* __restrict__ Kb,
                       const ushort* __restrict__ Vt, const int* __restrict__ mask,
                       float* __restrict__ out) {
    __shared__ alignas(16) ushort Ks[2][32][128];   // 16 KB [buf][key][hd-chunk swizzled]
    __shared__ alignas(16) ushort Vs[2][128][32];   // 16 KB [buf][hd][key-chunk swizzled]
#if !HAS_PERMSWAP
    __shared__ alignas(16) ushort Pl[4][16][40];    // fallback P scratch
#endif
    const int blk = blockIdx.x;
    const int h = blk & 7, qt = (blk >> 3) & 31, b = blk >> 8;
    const int t = threadIdx.x;
    const int w = t >> 6, lane = t & 63, quad = lane >> 4, li = lane & 15;
    const int q0 = qt * 64 + w * 16;
    const ushort* Qh = Qb + (size_t)(b * H_ + h) * L_ * HD_;
    const ushort* Kh = Kb + (size_t)(b * H_ + h) * L_ * HD_;
    const ushort* Vh = Vt + (size_t)(b * H_ + h) * HD_ * L_;
    const int* mb = mask + b * L_;

    // block-uniform unmasked-key count (recomputed from mask: no d_out dependency)
    int cm = 0;
    for (int c = lane; c < L_; c += 64) cm += mb[c];
    cm += __shfl_xor(cm, 32, 64);
    cm += __shfl_xor(cm, 16, 64);
    cm += __shfl_xor(cm, 8, 64);
    cm += __shfl_xor(cm, 4, 64);
    cm += __shfl_xor(cm, 2, 64);
    cm += __shfl_xor(cm, 1, 64);
    const int cnt = cm;
    int cnt_pad = (cnt + 31) & ~31;
    if (cnt_pad < 32) cnt_pad = 32;              // NaN guard (unreachable for real input)

    // DMA source pointers (lane-dependent; per-tile offset added at issue).
    const ushort* kgp[2]; const ushort* vgp[2];
    for (int i = 0; i < 2; i++) {
        int seg = w * 2 + i;                       // 0..7
        int key = seg * 4 + (lane >> 4);           // 0..31
        int ck  = (lane & 15) ^ (key & 15);
        kgp[i] = Kh + (size_t)key * HD_ + ck * 8;
        int hd  = seg * 16 + (lane >> 2);          // 0..127
        int cv  = (lane & 3) ^ (hd & 3);
        vgp[i] = Vh + (size_t)hd * L_ + cv * 8;
    }

    // prologue: DMA tile 0 into buf 0
    for (int i = 0; i < 2; i++) dma16(kgp[i], &Ks[0][0][0] + (w * 2 + i) * 512);
    for (int i = 0; i < 2; i++) dma16(vgp[i], &Vs[0][0][0] + (w * 2 + i) * 512);

    // Q as B-fragments (global, linear): qf[kf], n = q = li
    bf16x8 qf[4];
    for (int kf = 0; kf < 4; kf++)
        qf[kf] = *(const bf16x8*)&Qh[(size_t)(q0 + li) * HD_ + kf * 32 + quad * 8];

    bf16x8 ones;
    for (int i = 0; i < 8; i++) ones[i] = (short)0x3F80;  // bf16 1.0

    float mrun = -1e30f;
    f32x4 lsum = {};     // row-space softmax denominator: row q = quad*4+r (MFMA-accumulated)
    f32x4 acc[8] = {};   // PV C-layout: row q = quad*4+r, col hd = li + 16*nf2

    int buf = 0;
    for (int n0 = 0; n0 < cnt_pad; n0 += 32, buf ^= 1) {
        __syncthreads();   // buf's DMA drained+visible; all waves past prior buf reads

        if (n0 + 32 < cnt_pad) {  // uniform: issue next tile's DMA into other buffer
            int nb = buf ^ 1;
            for (int i = 0; i < 2; i++)
                dma16(kgp[i] + (size_t)(n0 + 32) * HD_, &Ks[nb][0][0] + (w * 2 + i) * 512);
            for (int i = 0; i < 2; i++)
                dma16(vgp[i] + (n0 + 32), &Vs[nb][0][0] + (w * 2 + i) * 512);
        }

        // S^T = K(A) x Q^T(B): s[mt][r]: key = mt*16+quad*4+r, q = li  (log2 units)
        f32x4 s[2] = {};
        __builtin_amdgcn_s_setprio(1);
        for (int kf = 0; kf < 4; kf++) {
            bf16x8 kfr[2];
            for (int mt = 0; mt < 2; mt++)
                kfr[mt] = *(const bf16x8*)&Ks[buf][mt * 16 + li][((kf * 4 + quad) ^ li) * 8];
            for (int mt = 0; mt < 2; mt++)
                s[mt] = __builtin_amdgcn_mfma_f32_16x16x32_bf16(kfr[mt], qf[kf], s[mt], 0, 0, 0);
        }
        __builtin_amdgcn_s_setprio(0);

        if (n0 + 32 > cnt) {  // tail tile only (uniform branch): clamp pad keys
            for (int mt = 0; mt < 2; mt++)
                for (int r = 0; r < 4; r++)
                    if (n0 + mt * 16 + quad * 4 + r >= cnt) s[mt][r] = -1e30f;
        }

        // softmax over this 32-key tile (q = li), log2 domain: p = exp2(s - m)
        float a0 = fmaxf(fmaxf(s[0][0], s[0][1]), fmaxf(s[0][2], s[0][3]));
        float a1 = fmaxf(fmaxf(s[1][0], s[1][1]), fmaxf(s[1][2], s[1][3]));
        float nm = qmax4(fmaxf(a0, a1));

        // defer-max (T13, THR=8 in log2 units): only when some row's tile max
        // outgrows its stale running max by >8 do we install the new max and
        // rescale acc+lsum. P values stay bounded by 2^8; fp32 accum absorbs it.
        if (!__all(nm <= mrun + 8.f)) {
            float mnew = fmaxf(mrun, nm);
            float alpha = exp2_fast(mrun - mnew);
            mrun = mnew;
            int sb = (lane & 48) | (quad * 4);     // lane with li = quad*4 (+r)
            float ar0 = __shfl(alpha, sb + 0, 64);
            float ar1 = __shfl(alpha, sb + 1, 64);
            float ar2 = __shfl(alpha, sb + 2, 64);
            float ar3 = __shfl(alpha, sb + 3, 64);
            lsum[0] *= ar0; lsum[1] *= ar1; lsum[2] *= ar2; lsum[3] *= ar3;
            for (int nf2 = 0; nf2 < 8; nf2++) {
                acc[nf2][0] *= ar0;
                acc[nf2][1] *= ar1;
                acc[nf2][2] *= ar2;
                acc[nf2][3] *= ar3;
            }
        }

        for (int mt = 0; mt < 2; mt++)
            for (int r = 0; r < 4; r++)
                s[mt][r] = exp2_fast(s[mt][r] - mrun);

        // build PV A-fragment pa[reg] = P_bf16[q=li][key = quad*8 + reg]
        bf16x8 pa;
#if HAS_PERMSWAP
        {
            unsigned c0 = cvt_pk_bf16(s[0][0], s[0][1]);
            unsigned c1 = cvt_pk_bf16(s[0][2], s[0][3]);
            unsigned c2 = cvt_pk_bf16(s[1][0], s[1][1]);
            unsigned c3 = cvt_pk_bf16(s[1][2], s[1][3]);
            uint2v x02 = __builtin_amdgcn_permlane32_swap(c0, c2, false, false);
            uint2v u02 = __builtin_amdgcn_permlane16_swap(x02[0], x02[1], false, false);
            uint2v x13 = __builtin_amdgcn_permlane32_swap(c1, c3, false, false);
            uint2v u13 = __builtin_amdgcn_permlane16_swap(x13[0], x13[1], false, false);
            uint4v paw;
            paw[0] = u02[0];   // keys 8q+0,1
            paw[1] = u13[0];   // keys 8q+2,3
            paw[2] = u02[1];   // keys 8q+4,5
            paw[3] = u13[1];   // keys 8q+6,7
            pa = __builtin_bit_cast(bf16x8, paw);
        }
#else
        {
            for (int mt = 0; mt < 2; mt++) {
                uint2 pk;
                pk.x = cvt_pk_bf16(s[mt][0], s[mt][1]);
                pk.y = cvt_pk_bf16(s[mt][2], s[mt][3]);
                *(uint2*)&Pl[w][li][mt * 16 + quad * 4] = pk;
            }
            pa = *(const bf16x8*)&Pl[w][li][quad * 8];
        }
#endif

        // row-sum of P via MFMA (B = ones) + PV from staged LDS
        __builtin_amdgcn_s_setprio(1);
        lsum = __builtin_amdgcn_mfma_f32_16x16x32_bf16(pa, ones, lsum, 0, 0, 0);
        for (int nf2 = 0; nf2 < 8; nf2++) {
            bf16x8 vb = *(const bf16x8*)&Vs[buf][nf2 * 16 + li][(quad ^ (li & 3)) * 8];
            acc[nf2] = __builtin_amdgcn_mfma_f32_16x16x32_bf16(pa, vb, acc[nf2], 0, 0, 0);
        }
        __builtin_amdgcn_s_setprio(0);
    }

    // epilogue: lsum already in row space -> direct reciprocal, float4 stores
    float i0 = 1.0f / lsum[0];
    float i1 = 1.0f / lsum[1];
    float i2 = 1.0f / lsum[2];
    float i3 = 1.0f / lsum[3];
    int l = q0 + quad * 4;
    for (int nf2 = 0; nf2 < 8; nf2++) {
        int d = h * HD_ + nf2 * 16 + li;
        float4 o4 = { acc[nf2][0] * i0, acc[nf2][1] * i1,
                      acc[nf2][2] * i2, acc[nf2][3] * i3 };
        *(float4*)&out[((size_t)(b * D_ + d)) * L_ + l] = o4;
    }
}

extern "C" void kernel_launch(void* const* d_in, const int* in_sizes, int n_in,
                              void* d_out, int out_size, void* d_ws, size_t ws_size,
                              hipStream_t stream) {
    // Bind inputs by element count (all distinct).
    const float* query = nullptr;  // 4*1024*2048 = 8388608
    const int*   mask  = nullptr;  // 4*2048     = 8192
    const float* W1    = nullptr;  // 2048*1024  = 2097152
    const float* Wq    = nullptr;  // 1024*1024  = 1048576
    for (int i = 0; i < n_in; i++) {
        switch (in_sizes[i]) {
            case 8388608: query = (const float*)d_in[i]; break;
            case 8192:    mask  = (const int*)d_in[i];   break;
            case 2097152: W1    = (const float*)d_in[i]; break;
            case 1048576: Wq    = (const float*)d_in[i]; break;
        }
    }
    float* out = (float*)d_out;  // [4,1024,2048] fp32 (reference output dtype)

    if (ws_size < 50331648u || !query || !mask || !W1 || !Wq) {
        hipLaunchKernelGGL(k_zero_out, dim3((out_size + 255) / 256), dim3(256), 0, stream,
                           out, out_size);
        return;
    }

    // d_out (32 MB fp32) is dead until k_attn -> use its head as projection scratch.
    // cidx/cnt also live here: written by k_prep, read ONLY by k_proj (pre-attn).
    ushort* Wb = (ushort*)d_out;                       // [3072][1024]      6291456 B
    ushort* Xt = (ushort*)((char*)d_out + 6291456);    // [4][2048][1024]  16777216 B
    int* cidx  = (int*)((char*)d_out + 23068672);      // [4][2048]           32768 B
    int* cnt   = (int*)((char*)d_out + 23101440);      // [4]                    16 B
    char* ws = (char*)d_ws;                            // Qb|Kb|Vt = 48 MB <= gate
    ushort* Qb = (ushort*)(ws + 0);
    ushort* Kb = (ushort*)(ws + 16777216);
    ushort* Vt = (ushort*)(ws + 33554432);

    hipLaunchKernelGGL(k_prep, dim3(4 + 2048 + 3072), dim3(256), 0, stream,
                       query, W1, Wq, mask, Wb, Xt, cidx, cnt);
    hipLaunchKernelGGL(k_proj, dim3(1536), dim3(256), 0, stream, Wb, Xt, cidx, cnt, Qb, Kb, Vt);
    hipLaunchKernelGGL(k_attn, dim3(1024), dim3(256), 0, stream, Qb, Kb, Vt, mask, out);
}

// Round 13
// 208.617 us; speedup vs baseline: 1.0533x; 1.0533x over previous
//
#include <hip/hip_runtime.h>
#include <hip/hip_bf16.h>

#define B_  4
#define D_  1024
#define L_  2048
#define H_  8
#define HD_ 128

typedef __attribute__((ext_vector_type(8))) short bf16x8;
typedef __attribute__((ext_vector_type(4))) float f32x4;
typedef __attribute__((ext_vector_type(2))) unsigned uint2v;
typedef __attribute__((ext_vector_type(4))) unsigned uint4v;

#if __has_builtin(__builtin_amdgcn_permlane16_swap) && __has_builtin(__builtin_amdgcn_permlane32_swap)
#define HAS_PERMSWAP 1
#else
#define HAS_PERMSWAP 0
#endif

static __device__ __forceinline__ ushort f2bf(float f) {
    // round-to-nearest-even fp32 -> bf16 (finite inputs only)
    unsigned u = __float_as_uint(f);
    unsigned r = (u + 0x7fffu + ((u >> 16) & 1u)) >> 16;
    return (ushort)r;
}

// packed fp32x2 -> bf16x2 (RNE) in one instruction; lo = first arg
static __device__ __forceinline__ unsigned cvt_pk_bf16(float lo, float hi) {
    unsigned r;
    asm("v_cvt_pk_bf16_f32 %0, %1, %2" : "=v"(r) : "v"(lo), "v"(hi));
    return r;
}

// hardware exp2 (v_exp_f32)
static __device__ __forceinline__ float exp2_fast(float x) {
#if __has_builtin(__builtin_amdgcn_exp2f)
    return __builtin_amdgcn_exp2f(x);
#else
    return exp2f(x);
#endif
}

// max over the 4 quads (lanes {li, li+16, li+32, li+48}) — pure VALU if permlane
static __device__ __forceinline__ float qmax4(float x) {
#if HAS_PERMSWAP
    uint2v a = __builtin_amdgcn_permlane16_swap(__float_as_uint(x), __float_as_uint(x), false, false);
    float y = fmaxf(__uint_as_float(a[0]), __uint_as_float(a[1]));
    uint2v b = __builtin_amdgcn_permlane32_swap(__float_as_uint(y), __float_as_uint(y), false, false);
    return fmaxf(__uint_as_float(b[0]), __uint_as_float(b[1]));
#else
    x = fmaxf(x, __shfl_xor(x, 16, 64));
    return fmaxf(x, __shfl_xor(x, 32, 64));
#endif
}

// async 16B global->LDS DMA (dest = wave-uniform LDS base + lane*16)
static __device__ __forceinline__ void dma16(const ushort* g, ushort* l) {
    __builtin_amdgcn_global_load_lds(
        (const __attribute__((address_space(1))) void*)g,
        (__attribute__((address_space(3))) void*)l, 16, 0, 0);
}

// ---------------- signal kernel: zero output ----------------
__global__ void k_zero_out(float* __restrict__ out, int n) {
    int i = blockIdx.x * 256 + threadIdx.x;
    if (i < n) out[i] = 0.f;
}

// ---------------- Kernel A (fused prep): scan | transpose | convert_w -----------
// role by blockIdx range (block-uniform): [0,4) mask scan (FIRST so its serial
// waves overlap the bulk, no tail), [4,2052) transpose 64x64, [2052,5124) convert.
__global__ void k_prep(const float* __restrict__ q, const float* __restrict__ W1,
                       const float* __restrict__ Wq, const int* __restrict__ mask,
                       ushort* __restrict__ Wb, ushort* __restrict__ Xt,
                       int* __restrict__ cidx, int* __restrict__ cnt) {
    __shared__ float tile[64][65];     // 16.6 KB (transpose role)
    const int bid = blockIdx.x, t = threadIdx.x;
    if (bid < 4) {
        // mask scan: cidx[b][j] = original l of j-th unmasked key; pad 0; cnt[b]
        int b = bid;
        if (t < 64) {
            int lane = t;
            const int* mb = mask + b * L_;
            int base = 0;
            for (int c = 0; c < L_; c += 64) {
                int m = mb[c + lane];
                unsigned long long bal = __ballot(m != 0);
                int pre = __popcll(bal & ((1ull << lane) - 1ull));
                if (m) cidx[b * L_ + base + pre] = c + lane;
                base += __popcll(bal);
            }
            for (int j = base + lane; j < L_; j += 64) cidx[b * L_ + j] = 0;
            if (lane == 0) cnt[b] = base;
        }
    } else if (bid < 4 + 2048) {
        // transpose query[b][d][l] fp32 -> Xt[b][l][d] bf16, 64x64 tile
        int tb = bid - 4;
        int bx = tb & 31, by = (tb >> 5) & 15, bz = tb >> 9;
        int l0 = bx * 64, d0 = by * 64;
        int rr = t >> 4, cc = t & 15;            // rr 0..15, cc 0..15
        const float* src = q + (size_t)bz * D_ * L_;
        for (int i = 0; i < 4; i++) {
            int r = rr + 16 * i;                 // d-row 0..63
            float4 v = *(const float4*)&src[(size_t)(d0 + r) * L_ + l0 + cc * 4];
            tile[r][cc * 4 + 0] = v.x;
            tile[r][cc * 4 + 1] = v.y;
            tile[r][cc * 4 + 2] = v.z;
            tile[r][cc * 4 + 3] = v.w;
        }
        __syncthreads();
        ushort* dst = Xt + (size_t)bz * L_ * D_;
        for (int i = 0; i < 4; i++) {
            int lr = rr + 16 * i;                // l-row 0..63
            uint2 o;
            o.x = cvt_pk_bf16(tile[cc * 4 + 0][lr], tile[cc * 4 + 1][lr]);
            o.y = cvt_pk_bf16(tile[cc * 4 + 2][lr], tile[cc * 4 + 3][lr]);
            *(uint2*)&dst[(size_t)(l0 + lr) * D_ + d0 + cc * 4] = o;
        }
    } else {
        // W1||Wq fp32 -> bf16 Wb [3072][1024]
        int i = (bid - 2052) * 256 + t;
        const int n1 = 2 * D_ * D_ / 4;
        float4 v = (i < n1) ? ((const float4*)W1)[i] : ((const float4*)Wq)[i - n1];
        ushort4 o;
        o.x = f2bf(v.x); o.y = f2bf(v.y); o.z = f2bf(v.z); o.w = f2bf(v.w);
        ((ushort4*)Wb)[i] = o;
    }
}

// ---------------- Kernel B: projection GEMM (MFMA, XCD supertiles, T4 vmcnt) ----
// Depth-2 prefetch pipeline with COUNTED vmcnt (the m218/T4 variant): 3 buffers
// of BK=32 (48 KB LDS, 3 blocks/CU). Per iteration:
//   vmcnt(4) -> s_barrier -> issue tile idx+2 -> compute tile idx
// Each tile's 4 DMAs stay in flight across TWO barriers (~2 compute phases),
// unlike __syncthreads() which drains vmcnt(0) every step (r6/r11 nulls).
// bid -> XCD-chunked 4x4 supertile decode (FETCH 87->46 MB, proven r6/r7).
// Epilogue: r9's direct stores (r12's LDS-staged stores regressed).
__launch_bounds__(256)
__global__ void k_proj(const ushort* __restrict__ Wb, const ushort* __restrict__ Xt,
                       const int* __restrict__ cidx, const int* __restrict__ cnt,
                       ushort* __restrict__ Qb, ushort* __restrict__ Kb,
                       ushort* __restrict__ Vt) {
    // A tiles at [buf*4096], B tiles at [12288 + buf*4096] (ushorts); buf 0..2
    __shared__ alignas(16) ushort sh[3 * 4096 * 2];   // 48 KB
    // ---- XCD-chunked supertile decode (bijective on 1536) ----
    const int bid = blockIdx.x;
    const int xcd = bid & 7, j = bid >> 3;       // j 0..191: per-XCD stream
    const int wid = xcd * 192 + j;               // contiguous chunk per XCD
    const int st = wid >> 4, m = wid & 15;       // supertile 0..95, member 0..15
    const int b  = st / 24;                      // batch
    const int sr = st % 24;
    const int sx = sr & 3, sy = sr >> 2;         // supergrid 4x x 6y
    const int x  = sx * 4 + (m & 3);             // l-tile 0..15
    const int y  = sy * 4 + (m >> 2);            // o-tile 0..23
    const int o0 = y * 128;
    const int l0 = x * 128;
    const int type = o0 >> 10;                   // 0=K 1=V 2=Q (tile never crosses)
    if (type < 2) {                              // compacted key space: skip dead tiles
        int tiles = (cnt[b] + 127) >> 7;
        if (x >= tiles) return;                  // uniform; before any barrier
    }
    const int t = threadIdx.x;
    const int wave = t >> 6, lane = t & 63, quad = lane >> 4, li = lane & 15;
    const int wm = wave >> 1, wn = wave & 1;
    const ushort* Xb = Xt + (size_t)b * L_ * D_;

    // staging (BK=32): issue i covers rows i*64 + (t>>2), phys chunk p = t&3 (16B).
    // slot (row,p) holds global 16B chunk g = p ^ ((row + (row>>2)) & 3)
    const int srow = t >> 2;                     // 0..63
    const int csw = ((srow + (srow >> 2)) & 3);
    const int g = (t & 3) ^ csw;
    const ushort* aSrc[2];
    const ushort* bSrc[2];
    for (int i = 0; i < 2; i++) {
        int r = i * 64 + srow;
        aSrc[i] = Wb + (size_t)(o0 + r) * D_ + g * 8;
        int l = l0 + r;
        int gl = (type < 2) ? cidx[b * L_ + l] : l;
        bSrc[i] = Xb + (size_t)gl * D_ + g * 8;
    }

    f32x4 acc[4][4] = {};

    // per-lane fragment read offsets (logical chunk = quad, swizzled; r11-verified)
    const int fsw = (li + (li >> 2)) & 3;
    const int fchunk = (quad ^ fsw) * 8;

    // prologue: stage tiles 0,1 into buffers 0,1 (4 DMAs per tile per thread)
    for (int tt = 0; tt < 2; tt++) {
        ushort* Ad = sh + tt * 4096;
        ushort* Bd = sh + 12288 + tt * 4096;
        for (int i = 0; i < 2; i++) dma16(aSrc[i] + tt * 32, Ad + (i * 256 + wave * 64) * 8);
        for (int i = 0; i < 2; i++) dma16(bSrc[i] + tt * 32, Bd + (i * 256 + wave * 64) * 8);
    }

    int cb = 0;                                  // buffer holding tile idx
    for (int idx = 0; idx < 32; idx++) {
        // counted wait: my tile-idx loads done; future tiles' loads stay in flight
        if (idx < 31) asm volatile("s_waitcnt vmcnt(4)" ::: "memory");
        else          asm volatile("s_waitcnt vmcnt(0)" ::: "memory");
        __builtin_amdgcn_sched_barrier(0);
        __builtin_amdgcn_s_barrier();            // all waves' tile-idx loads landed;
                                                 // all waves done computing tile idx-1
        __builtin_amdgcn_sched_barrier(0);

        if (idx + 2 < 32) {                      // issue tile idx+2 into buf (idx+2)%3
            int ib = cb + 2; if (ib >= 3) ib -= 3;
            int ko = (idx + 2) * 32;
            ushort* Ad = sh + ib * 4096;
            ushort* Bd = sh + 12288 + ib * 4096;
            for (int i = 0; i < 2; i++) dma16(aSrc[i] + ko, Ad + (i * 256 + wave * 64) * 8);
            for (int i = 0; i < 2; i++) dma16(bSrc[i] + ko, Bd + (i * 256 + wave * 64) * 8);
        }

        const ushort* Ab = sh + cb * 4096;
        const ushort* Bb = sh + 12288 + cb * 4096;
        bf16x8 af[4], bfr[4];
        for (int mf = 0; mf < 4; mf++)
            af[mf] = *(const bf16x8*)&Ab[(wm * 64 + mf * 16 + li) * 32 + fchunk];
        for (int nf = 0; nf < 4; nf++)
            bfr[nf] = *(const bf16x8*)&Bb[(wn * 64 + nf * 16 + li) * 32 + fchunk];
        for (int mf = 0; mf < 4; mf++)
            for (int nf = 0; nf < 4; nf++)
                acc[mf][nf] = __builtin_amdgcn_mfma_f32_16x16x32_bf16(af[mf], bfr[nf], acc[mf][nf], 0, 0, 0);

        cb++; if (cb >= 3) cb = 0;
    }

    const float qscale = 0.1275174495450826f;   // HD^-0.5 * log2(e)
    for (int mf = 0; mf < 4; mf++) {
        int o = o0 + wm * 64 + mf * 16 + quad * 4;
        int c = o & 1023;
        int h = c >> 7, hd = c & 127;
        for (int nf = 0; nf < 4; nf++) {
            int l = l0 + wn * 64 + nf * 16 + li;
            f32x4 v = acc[mf][nf];
            if (type == 0) {
                uint2 kk;
                kk.x = cvt_pk_bf16(v[0], v[1]);
                kk.y = cvt_pk_bf16(v[2], v[3]);
                *(uint2*)&Kb[(((size_t)(b * H_ + h)) * L_ + l) * HD_ + hd] = kk;
            } else if (type == 1) {
                size_t base = (size_t)(b * H_ + h) * HD_;
                Vt[(base + hd + 0) * L_ + l] = f2bf(v[0]);
                Vt[(base + hd + 1) * L_ + l] = f2bf(v[1]);
                Vt[(base + hd + 2) * L_ + l] = f2bf(v[2]);
                Vt[(base + hd + 3) * L_ + l] = f2bf(v[3]);
            } else {
                uint2 qq;
                qq.x = cvt_pk_bf16(v[0] * qscale, v[1] * qscale);
                qq.y = cvt_pk_bf16(v[2] * qscale, v[3] * qscale);
                *(uint2*)&Qb[(((size_t)(b * H_ + h)) * L_ + l) * HD_ + hd] = qq;
            }
        }
    }
}

// ---------------- Kernel C: flash attention over COMPACTED keys ------------------
// block = (b, h, 64 q); 4 waves x 16 q; key blocks of 32; one barrier/iter.
// Softmax critical path has ZERO DS ops: max via permlane swaps (VALU), row-sum
// via one extra MFMA into a persistent row-space accumulator, P redistribution
// via permlane (no LDS round-trip). defer-max THR=8 (log2 units): keep a stale
// running max while tile maxes stay within 2^8 headroom -> rescale pass rare.
__launch_bounds__(256, 4)
__global__ void k_attn(const ushort* __restrict__ Qb, const ushort* __restrict__ Kb,
                       const ushort* __restrict__ Vt, const int* __restrict__ mask,
                       float* __restrict__ out) {
    __shared__ alignas(16) ushort Ks[2][32][128];   // 16 KB [buf][key][hd-chunk swizzled]
    __shared__ alignas(16) ushort Vs[2][128][32];   // 16 KB [buf][hd][key-chunk swizzled]
#if !HAS_PERMSWAP
    __shared__ alignas(16) ushort Pl[4][16][40];    // fallback P scratch
#endif
    const int blk = blockIdx.x;
    const int h = blk & 7, qt = (blk >> 3) & 31, b = blk >> 8;
    const int t = threadIdx.x;
    const int w = t >> 6, lane = t & 63, quad = lane >> 4, li = lane & 15;
    const int q0 = qt * 64 + w * 16;
    const ushort* Qh = Qb + (size_t)(b * H_ + h) * L_ * HD_;
    const ushort* Kh = Kb + (size_t)(b * H_ + h) * L_ * HD_;
    const ushort* Vh = Vt + (size_t)(b * H_ + h) * HD_ * L_;
    const int* mb = mask + b * L_;

    // block-uniform unmasked-key count (recomputed from mask: no d_out dependency)
    int cm = 0;
    for (int c = lane; c < L_; c += 64) cm += mb[c];
    cm += __shfl_xor(cm, 32, 64);
    cm += __shfl_xor(cm, 16, 64);
    cm += __shfl_xor(cm, 8, 64);
    cm += __shfl_xor(cm, 4, 64);
    cm += __shfl_xor(cm, 2, 64);
    cm += __shfl_xor(cm, 1, 64);
    const int cnt = cm;
    int cnt_pad = (cnt + 31) & ~31;
    if (cnt_pad < 32) cnt_pad = 32;              // NaN guard (unreachable for real input)

    // DMA source pointers (lane-dependent; per-tile offset added at issue).
    const ushort* kgp[2]; const ushort* vgp[2];
    for (int i = 0; i < 2; i++) {
        int seg = w * 2 + i;                       // 0..7
        int key = seg * 4 + (lane >> 4);           // 0..31
        int ck  = (lane & 15) ^ (key & 15);
        kgp[i] = Kh + (size_t)key * HD_ + ck * 8;
        int hd  = seg * 16 + (lane >> 2);          // 0..127
        int cv  = (lane & 3) ^ (hd & 3);
        vgp[i] = Vh + (size_t)hd * L_ + cv * 8;
    }

    // prologue: DMA tile 0 into buf 0
    for (int i = 0; i < 2; i++) dma16(kgp[i], &Ks[0][0][0] + (w * 2 + i) * 512);
    for (int i = 0; i < 2; i++) dma16(vgp[i], &Vs[0][0][0] + (w * 2 + i) * 512);

    // Q as B-fragments (global, linear): qf[kf], n = q = li
    bf16x8 qf[4];
    for (int kf = 0; kf < 4; kf++)
        qf[kf] = *(const bf16x8*)&Qh[(size_t)(q0 + li) * HD_ + kf * 32 + quad * 8];

    bf16x8 ones;
    for (int i = 0; i < 8; i++) ones[i] = (short)0x3F80;  // bf16 1.0

    float mrun = -1e30f;
    f32x4 lsum = {};     // row-space softmax denominator: row q = quad*4+r (MFMA-accumulated)
    f32x4 acc[8] = {};   // PV C-layout: row q = quad*4+r, col hd = li + 16*nf2

    int buf = 0;
    for (int n0 = 0; n0 < cnt_pad; n0 += 32, buf ^= 1) {
        __syncthreads();   // buf's DMA drained+visible; all waves past prior buf reads

        if (n0 + 32 < cnt_pad) {  // uniform: issue next tile's DMA into other buffer
            int nb = buf ^ 1;
            for (int i = 0; i < 2; i++)
                dma16(kgp[i] + (size_t)(n0 + 32) * HD_, &Ks[nb][0][0] + (w * 2 + i) * 512);
            for (int i = 0; i < 2; i++)
                dma16(vgp[i] + (n0 + 32), &Vs[nb][0][0] + (w * 2 + i) * 512);
        }

        // S^T = K(A) x Q^T(B): s[mt][r]: key = mt*16+quad*4+r, q = li  (log2 units)
        f32x4 s[2] = {};
        __builtin_amdgcn_s_setprio(1);
        for (int kf = 0; kf < 4; kf++) {
            bf16x8 kfr[2];
            for (int mt = 0; mt < 2; mt++)
                kfr[mt] = *(const bf16x8*)&Ks[buf][mt * 16 + li][((kf * 4 + quad) ^ li) * 8];
            for (int mt = 0; mt < 2; mt++)
                s[mt] = __builtin_amdgcn_mfma_f32_16x16x32_bf16(kfr[mt], qf[kf], s[mt], 0, 0, 0);
        }
        __builtin_amdgcn_s_setprio(0);

        if (n0 + 32 > cnt) {  // tail tile only (uniform branch): clamp pad keys
            for (int mt = 0; mt < 2; mt++)
                for (int r = 0; r < 4; r++)
                    if (n0 + mt * 16 + quad * 4 + r >= cnt) s[mt][r] = -1e30f;
        }

        // softmax over this 32-key tile (q = li), log2 domain: p = exp2(s - m)
        float a0 = fmaxf(fmaxf(s[0][0], s[0][1]), fmaxf(s[0][2], s[0][3]));
        float a1 = fmaxf(fmaxf(s[1][0], s[1][1]), fmaxf(s[1][2], s[1][3]));
        float nm = qmax4(fmaxf(a0, a1));

        // defer-max (T13, THR=8 in log2 units): only when some row's tile max
        // outgrows its stale running max by >8 do we install the new max and
        // rescale acc+lsum. P values stay bounded by 2^8; fp32 accum absorbs it.
        if (!__all(nm <= mrun + 8.f)) {
            float mnew = fmaxf(mrun, nm);
            float alpha = exp2_fast(mrun - mnew);
            mrun = mnew;
            int sb = (lane & 48) | (quad * 4);     // lane with li = quad*4 (+r)
            float ar0 = __shfl(alpha, sb + 0, 64);
            float ar1 = __shfl(alpha, sb + 1, 64);
            float ar2 = __shfl(alpha, sb + 2, 64);
            float ar3 = __shfl(alpha, sb + 3, 64);
            lsum[0] *= ar0; lsum[1] *= ar1; lsum[2] *= ar2; lsum[3] *= ar3;
            for (int nf2 = 0; nf2 < 8; nf2++) {
                acc[nf2][0] *= ar0;
                acc[nf2][1] *= ar1;
                acc[nf2][2] *= ar2;
                acc[nf2][3] *= ar3;
            }
        }

        for (int mt = 0; mt < 2; mt++)
            for (int r = 0; r < 4; r++)
                s[mt][r] = exp2_fast(s[mt][r] - mrun);

        // build PV A-fragment pa[reg] = P_bf16[q=li][key = quad*8 + reg]
        bf16x8 pa;
#if HAS_PERMSWAP
        {
            unsigned c0 = cvt_pk_bf16(s[0][0], s[0][1]);
            unsigned c1 = cvt_pk_bf16(s[0][2], s[0][3]);
            unsigned c2 = cvt_pk_bf16(s[1][0], s[1][1]);
            unsigned c3 = cvt_pk_bf16(s[1][2], s[1][3]);
            uint2v x02 = __builtin_amdgcn_permlane32_swap(c0, c2, false, false);
            uint2v u02 = __builtin_amdgcn_permlane16_swap(x02[0], x02[1], false, false);
            uint2v x13 = __builtin_amdgcn_permlane32_swap(c1, c3, false, false);
            uint2v u13 = __builtin_amdgcn_permlane16_swap(x13[0], x13[1], false, false);
            uint4v paw;
            paw[0] = u02[0];   // keys 8q+0,1
            paw[1] = u13[0];   // keys 8q+2,3
            paw[2] = u02[1];   // keys 8q+4,5
            paw[3] = u13[1];   // keys 8q+6,7
            pa = __builtin_bit_cast(bf16x8, paw);
        }
#else
        {
            for (int mt = 0; mt < 2; mt++) {
                uint2 pk;
                pk.x = cvt_pk_bf16(s[mt][0], s[mt][1]);
                pk.y = cvt_pk_bf16(s[mt][2], s[mt][3]);
                *(uint2*)&Pl[w][li][mt * 16 + quad * 4] = pk;
            }
            pa = *(const bf16x8*)&Pl[w][li][quad * 8];
        }
#endif

        // row-sum of P via MFMA (B = ones) + PV from staged LDS
        __builtin_amdgcn_s_setprio(1);
        lsum = __builtin_amdgcn_mfma_f32_16x16x32_bf16(pa, ones, lsum, 0, 0, 0);
        for (int nf2 = 0; nf2 < 8; nf2++) {
            bf16x8 vb = *(const bf16x8*)&Vs[buf][nf2 * 16 + li][(quad ^ (li & 3)) * 8];
            acc[nf2] = __builtin_amdgcn_mfma_f32_16x16x32_bf16(pa, vb, acc[nf2], 0, 0, 0);
        }
        __builtin_amdgcn_s_setprio(0);
    }

    // epilogue: lsum already in row space -> direct reciprocal, float4 stores
    float i0 = 1.0f / lsum[0];
    float i1 = 1.0f / lsum[1];
    float i2 = 1.0f / lsum[2];
    float i3 = 1.0f / lsum[3];
    int l = q0 + quad * 4;
    for (int nf2 = 0; nf2 < 8; nf2++) {
        int d = h * HD_ + nf2 * 16 + li;
        float4 o4 = { acc[nf2][0] * i0, acc[nf2][1] * i1,
                      acc[nf2][2] * i2, acc[nf2][3] * i3 };
        *(float4*)&out[((size_t)(b * D_ + d)) * L_ + l] = o4;
    }
}

extern "C" void kernel_launch(void* const* d_in, const int* in_sizes, int n_in,
                              void* d_out, int out_size, void* d_ws, size_t ws_size,
                              hipStream_t stream) {
    // Bind inputs by element count (all distinct).
    const float* query = nullptr;  // 4*1024*2048 = 8388608
    const int*   mask  = nullptr;  // 4*2048     = 8192
    const float* W1    = nullptr;  // 2048*1024  = 2097152
    const float* Wq    = nullptr;  // 1024*1024  = 1048576
    for (int i = 0; i < n_in; i++) {
        switch (in_sizes[i]) {
            case 8388608: query = (const float*)d_in[i]; break;
            case 8192:    mask  = (const int*)d_in[i];   break;
            case 2097152: W1    = (const float*)d_in[i]; break;
            case 1048576: Wq    = (const float*)d_in[i]; break;
        }
    }
    float* out = (float*)d_out;  // [4,1024,2048] fp32 (reference output dtype)

    if (ws_size < 50331648u || !query || !mask || !W1 || !Wq) {
        hipLaunchKernelGGL(k_zero_out, dim3((out_size + 255) / 256), dim3(256), 0, stream,
                           out, out_size);
        return;
    }

    // d_out (32 MB fp32) is dead until k_attn -> use its head as projection scratch.
    // cidx/cnt also live here: written by k_prep, read ONLY by k_proj (pre-attn).
    ushort* Wb = (ushort*)d_out;                       // [3072][1024]      6291456 B
    ushort* Xt = (ushort*)((char*)d_out + 6291456);    // [4][2048][1024]  16777216 B
    int* cidx  = (int*)((char*)d_out + 23068672);      // [4][2048]           32768 B
    int* cnt   = (int*)((char*)d_out + 23101440);      // [4]                    16 B
    char* ws = (char*)d_ws;                            // Qb|Kb|Vt = 48 MB <= gate
    ushort* Qb = (ushort*)(ws + 0);
    ushort* Kb = (ushort*)(ws + 16777216);
    ushort* Vt = (ushort*)(ws + 33554432);

    hipLaunchKernelGGL(k_prep, dim3(4 + 2048 + 3072), dim3(256), 0, stream,
                       query, W1, Wq, mask, Wb, Xt, cidx, cnt);
    hipLaunchKernelGGL(k_proj, dim3(1536), dim3(256), 0, stream, Wb, Xt, cidx, cnt, Qb, Kb, Vt);
    hipLaunchKernelGGL(k_attn, dim3(1024), dim3(256), 0, stream, Qb, Kb, Vt, mask, out);
}